// Round 5
// baseline (260.469 us; speedup 1.0000x reference)
//
#include <hip/hip_runtime.h>
#include <math.h>

// TopKRouter: logits = x(16384x2048) @ W(2048x64) + b; softmax E=64; top-2.
// Output: d_out[0:32768] = indices (as float), d_out[32768:65536] = probs.
//
// fp16 split-3 MFMA path (x = xh + xl*2^-11, W likewise, lo pre-scaled 2^11).
// Round 5: K-split 4-way. Block = 4 waves owns 16 rows; wave w does K range
// [w*512,(w+1)*512) with the round-4 register pipeline; partials reduced via
// LDS; wave 0 does softmax + top-2. Grid 1024 blocks -> 4 waves/SIMD.

#define D_DIM 2048
#define E_DIM 64
#define M_DIM 16384
#define BK 32
#define KSEG (D_DIM / 4)        // 512 per wave
#define NCH  (KSEG / BK)        // 16 chunks per wave

typedef _Float16 half8 __attribute__((ext_vector_type(8)));
typedef float floatx4 __attribute__((ext_vector_type(4)));

// ---------------- kernel 1: W split + transpose ----------------
// wsT halves: hi[n][k] at n*D_DIM + k (n<64), lo at (64+n)*D_DIM + k
__global__ __launch_bounds__(256) void split_w_kernel(
    const float* __restrict__ Wm, _Float16* __restrict__ wsT)
{
    __shared__ float t[64][65];
    const int tid = threadIdx.x;
    const int k0  = blockIdx.x * 64;

    #pragma unroll
    for (int p = 0; p < 16; p++) {
        int i  = p * 256 + tid;
        int kk = i >> 6, n = i & 63;
        t[n][kk] = Wm[(size_t)(k0 + kk) * E_DIM + n];
    }
    __syncthreads();
    #pragma unroll
    for (int p = 0; p < 16; p++) {
        int i  = p * 256 + tid;
        int kk = i & 63, n = i >> 6;
        float v = t[n][kk];
        _Float16 h = (_Float16)v;
        _Float16 l = (_Float16)((v - (float)h) * 2048.0f);
        wsT[(size_t)n * D_DIM + k0 + kk]           = h;
        wsT[(size_t)(E_DIM + n) * D_DIM + k0 + kk] = l;
    }
}

// ---------------- kernel 2: K-split MFMA GEMM + softmax + top-2 ----------------
__global__ __launch_bounds__(256, 4) void router_mfma_kernel(
    const float* __restrict__ x, const _Float16* __restrict__ wsT,
    const float* __restrict__ bias, float* __restrict__ out)
{
    const int lane = threadIdx.x & 63;
    const int wave = threadIdx.x >> 6;
    const int c    = lane & 15;
    const int quad = lane >> 4;
    const int r0   = blockIdx.x * 16;
    const int kb   = wave * KSEG;

    // A-frag: lane's row = r0 + c, k = kb + quad*8 + j
    const float* xp = x + (size_t)(r0 + c) * D_DIM + kb + quad * 8;
    // B-frag: lane's n = c + 16t, k = kb + quad*8 + j
    const _Float16* whp = wsT + (size_t)c * D_DIM + kb + quad * 8;
    const _Float16* wlp = whp + (size_t)E_DIM * D_DIM;

    floatx4 accm[4] = {};   // hi*hi
    floatx4 accl[4] = {};   // hi*lo' + lo'*hi (scaled 2^11)

    float4 xs0[2], xs1[2], xs2[2], xs3[2];
    half8  wh0[4], wl0[4], wh1[4], wl1[4];

    auto loadx = [&](int ch, float4* dst) {
        const int kk = ch < NCH ? ch : NCH - 1;
        const float* p = xp + kk * BK;
        dst[0] = *reinterpret_cast<const float4*>(p);
        dst[1] = *reinterpret_cast<const float4*>(p + 4);
    };
    auto loadw = [&](int ch, half8* h, half8* l) {
        const int kk = ch < NCH ? ch : NCH - 1;
        #pragma unroll
        for (int t = 0; t < 4; t++) {
            h[t] = *reinterpret_cast<const half8*>(whp + (size_t)t * 16 * D_DIM + kk * BK);
            l[t] = *reinterpret_cast<const half8*>(wlp + (size_t)t * 16 * D_DIM + kk * BK);
        }
    };
    auto compute = [&](const float4* xs, const half8* h, const half8* l) {
        const float xv[8] = {xs[0].x, xs[0].y, xs[0].z, xs[0].w,
                             xs[1].x, xs[1].y, xs[1].z, xs[1].w};
        half8 ah, al;
        #pragma unroll
        for (int j = 0; j < 8; j++) {
            _Float16 hh = (_Float16)xv[j];
            ah[j] = hh;
            al[j] = (_Float16)((xv[j] - (float)hh) * 2048.0f);
        }
        #pragma unroll
        for (int t = 0; t < 4; t++) {
            accm[t] = __builtin_amdgcn_mfma_f32_16x16x32_f16(ah, h[t], accm[t], 0, 0, 0);
            accl[t] = __builtin_amdgcn_mfma_f32_16x16x32_f16(al, h[t], accl[t], 0, 0, 0);
            accl[t] = __builtin_amdgcn_mfma_f32_16x16x32_f16(ah, l[t], accl[t], 0, 0, 0);
        }
    };

    loadx(0, xs0); loadx(1, xs1); loadw(0, wh0, wl0);

    #pragma unroll 1
    for (int ch = 0; ch < NCH; ch += 4) {
        loadx(ch + 2, xs2); loadw(ch + 1, wh1, wl1);
        compute(xs0, wh0, wl0);
        loadx(ch + 3, xs3); loadw(ch + 2, wh0, wl0);
        compute(xs1, wh1, wl1);
        loadx(ch + 4, xs0); loadw(ch + 3, wh1, wl1);
        compute(xs2, wh0, wl0);
        loadx(ch + 5, xs1); loadw(ch + 4, wh0, wl0);
        compute(xs3, wh1, wl1);
    }

    // ---- cross-wave partial reduction via LDS ----
    __shared__ float red[4][16][65];
    const float scale = 1.0f / 2048.0f;
    #pragma unroll
    for (int t = 0; t < 4; t++)
        #pragma unroll
        for (int i = 0; i < 4; i++)
            red[wave][quad * 4 + i][c + 16 * t] = accm[t][i] + accl[t][i] * scale;
    __syncthreads();

    if (wave != 0) return;

    // ---- epilogue (wave 0): C-layout row = quad*4+i, col = c + 16t ----
    float bvt[4];
    #pragma unroll
    for (int t = 0; t < 4; t++) bvt[t] = bias[c + 16 * t];

    #pragma unroll
    for (int i = 0; i < 4; i++) {
        const int row = quad * 4 + i;
        float lt[4];
        #pragma unroll
        for (int t = 0; t < 4; t++) {
            const int col = c + 16 * t;
            lt[t] = red[0][row][col] + red[1][row][col]
                  + red[2][row][col] + red[3][row][col] + bvt[t];
        }
        const float l0 = lt[0], l1 = lt[1], l2 = lt[2], l3 = lt[3];

        float m = fmaxf(fmaxf(l0, l1), fmaxf(l2, l3));
        #pragma unroll
        for (int off = 1; off < 16; off <<= 1)
            m = fmaxf(m, __shfl_xor(m, off, 64));

        const float e0 = expf(l0 - m), e1 = expf(l1 - m);
        const float e2 = expf(l2 - m), e3 = expf(l3 - m);
        float s = e0 + e1 + e2 + e3;
        #pragma unroll
        for (int off = 1; off < 16; off <<= 1)
            s += __shfl_xor(s, off, 64);

        const float p0 = e0 / s, p1 = e1 / s, p2 = e2 / s, p3 = e3 / s;

        // keys: (prob bits << 32) | (63 - expert); experts c, c+16, c+32, c+48
        const unsigned long long ka =
            ((unsigned long long)__float_as_uint(p0) << 32) | (unsigned long long)(63 - c);
        const unsigned long long kb_ =
            ((unsigned long long)__float_as_uint(p1) << 32) | (unsigned long long)(47 - c);
        const unsigned long long kc_ =
            ((unsigned long long)__float_as_uint(p2) << 32) | (unsigned long long)(31 - c);
        const unsigned long long kd =
            ((unsigned long long)__float_as_uint(p3) << 32) | (unsigned long long)(15 - c);

        unsigned long long hi1 = ka > kb_ ? ka : kb_, lo1 = ka > kb_ ? kb_ : ka;
        unsigned long long hi2 = kc_ > kd ? kc_ : kd, lo2 = kc_ > kd ? kd : kc_;
        unsigned long long k1 = hi1 > hi2 ? hi1 : hi2;
        unsigned long long mn = hi1 > hi2 ? hi2 : hi1;
        unsigned long long mx = lo1 > lo2 ? lo1 : lo2;
        unsigned long long k2 = mn > mx ? mn : mx;

        #pragma unroll
        for (int off = 1; off < 16; off <<= 1) {
            const unsigned long long o1 = __shfl_xor(k1, off, 64);
            const unsigned long long o2 = __shfl_xor(k2, off, 64);
            const unsigned long long n1 = k1 > o1 ? k1 : o1;
            const unsigned long long w1 = k1 > o1 ? o1 : k1;   // loser of firsts
            const unsigned long long w2 = k2 > o2 ? k2 : o2;   // best of seconds
            k1 = n1;
            k2 = w1 > w2 ? w1 : w2;
        }

        if (c == 0) {
            const int gr = r0 + row;
            out[gr * 2 + 0] = (float)(63 - (int)(k1 & 0xFFFFFFFFull));
            out[gr * 2 + 1] = (float)(63 - (int)(k2 & 0xFFFFFFFFull));
            out[M_DIM * 2 + gr * 2 + 0] = __uint_as_float((unsigned)(k1 >> 32));
            out[M_DIM * 2 + gr * 2 + 1] = __uint_as_float((unsigned)(k2 >> 32));
        }
    }
}

extern "C" void kernel_launch(void* const* d_in, const int* in_sizes, int n_in,
                              void* d_out, int out_size, void* d_ws, size_t ws_size,
                              hipStream_t stream) {
    const float* x  = (const float*)d_in[0];
    const float* Wm = (const float*)d_in[1];
    const float* b  = (const float*)d_in[2];
    float* out = (float*)d_out;
    _Float16* wsT = (_Float16*)d_ws;   // 2*64*2048*2 = 512 KB

    split_w_kernel<<<dim3(D_DIM / 64), dim3(256), 0, stream>>>(Wm, wsT);
    router_mfma_kernel<<<dim3(M_DIM / 16), dim3(256), 0, stream>>>(x, wsT, b, out);
}

// Round 6
// 202.667 us; speedup vs baseline: 1.2852x; 1.2852x over previous
//
#include <hip/hip_runtime.h>
#include <math.h>

// TopKRouter: logits = x(16384x2048) @ W(2048x64) + b; softmax E=64; top-2.
// Output: d_out[0:32768] = indices (as float), d_out[32768:65536] = probs.
//
// Round 6: kill address divergence. W pre-arranged in fragment-linear order
// (each frag load = base + lane*16B, contiguous 1KB/wave). x staged via LDS:
// coalesced global loads (4x256B segments/inst), in-register fp16 hi/lo split
// packed into uints, ds_write to per-wave private buffer (no barriers),
// ds_read MFMA A-frags. Split-3 numerics and K-split epilogue from round 5.

#define D_DIM 2048
#define E_DIM 64
#define M_DIM 16384
#define RM 32             // rows per block
#define BKC 64            // k per chunk
#define NCHW 8            // chunks per wave (512/64)
#define XSTR 68           // padded LDS row stride in uints

typedef _Float16 half8 __attribute__((ext_vector_type(8)));
typedef float floatx4 __attribute__((ext_vector_type(4)));
typedef unsigned int uint;

// ---------------- kernel 1: W split into fragment-linear layout ----------------
// For k-step g (32 k), tile t, plane p (0=hi,1=lo):
//   wsT[((g*4+t)*2+p)*512 + lane*8 + j] = plane(W[g*32 + quad*8 + j][16t + c]),
//   lane = quad*16 + c.
__global__ __launch_bounds__(256) void split_w_kernel(
    const float* __restrict__ Wm, _Float16* __restrict__ wsT)
{
    const int tid = threadIdx.x;
    const int n   = tid & 63;
    const int kk0 = tid >> 6;           // 0..3
    const int g   = blockIdx.x;         // 0..63
    #pragma unroll
    for (int r = 0; r < 8; r++) {
        const int kk = kk0 + r * 4;     // 0..31
        const float v = Wm[(size_t)(g * 32 + kk) * E_DIM + n];
        const _Float16 h = (_Float16)v;
        const _Float16 l = (_Float16)((v - (float)h) * 2048.0f);
        const int t = n >> 4, cc = n & 15, qd = kk >> 3, j = kk & 7;
        const size_t base = (size_t)((g * 4 + t) * 2) * 512 + (size_t)(qd * 16 + cc) * 8 + j;
        wsT[base]       = h;
        wsT[base + 512] = l;
    }
}

// ---------------- kernel 2: LDS-staged MFMA GEMM + softmax + top-2 ----------------
__global__ __launch_bounds__(256, 2) void router_mfma_kernel(
    const float* __restrict__ x, const _Float16* __restrict__ wsT,
    const float* __restrict__ bias, float* __restrict__ out)
{
    __shared__ uint xbuf[4][2][RM * XSTR];   // [wave][buf][row*XSTR + k]  (69632 B)

    const int lane = threadIdx.x & 63;
    const int wave = threadIdx.x >> 6;
    const int c    = lane & 15;
    const int quad = lane >> 4;
    const int r0   = blockIdx.x * RM;
    const int kb   = wave * (D_DIM / 4);     // 512 per wave

    // staging source: inst i covers rows i*4+quad, k = c*4 (+chunk*BKC)
    const float* xg = x + (size_t)(r0 + quad) * D_DIM + kb + c * 4;
    const _Float16* wbase = wsT + (size_t)(wave * 16) * 4096 + lane * 8;

    floatx4 accm[2][4] = {};
    floatx4 accl[2][4] = {};
    float4 xa[8], xb[8];
    half8 wh0[4], wl0[4], wh1[4], wl1[4];

    auto loadx = [&](int n, float4* dst) {
        const int nn = n < NCHW ? n : NCHW - 1;
        #pragma unroll
        for (int i = 0; i < 8; i++)
            dst[i] = *reinterpret_cast<const float4*>(xg + (size_t)i * 4 * D_DIM + nn * BKC);
    };
    auto stage = [&](int buf, const float4* src) {
        uint* dst = &xbuf[wave][buf][0];
        #pragma unroll
        for (int i = 0; i < 8; i++) {
            const int row = i * 4 + quad;
            const float v[4] = {src[i].x, src[i].y, src[i].z, src[i].w};
            uint p[4];
            #pragma unroll
            for (int q = 0; q < 4; q++) {
                const _Float16 h = (_Float16)v[q];
                const _Float16 l = (_Float16)((v[q] - (float)h) * 2048.0f);
                p[q] = (uint)__builtin_bit_cast(unsigned short, h)
                     | ((uint)__builtin_bit_cast(unsigned short, l) << 16);
            }
            *reinterpret_cast<uint4*>(dst + row * XSTR + c * 4) =
                make_uint4(p[0], p[1], p[2], p[3]);
        }
    };
    auto loadW = [&](int u, half8* wh, half8* wl) {   // u = local k-step 0..15
        const int uu = u < 16 ? u : 15;
        const _Float16* p = wbase + (size_t)uu * 4096;
        #pragma unroll
        for (int t = 0; t < 4; t++) {
            wh[t] = *reinterpret_cast<const half8*>(p + t * 1024);
            wl[t] = *reinterpret_cast<const half8*>(p + t * 1024 + 512);
        }
    };
    auto step = [&](int buf, int s, const half8* wh, const half8* wl) {
        #pragma unroll
        for (int tau = 0; tau < 2; tau++) {
            const uint* rp = &xbuf[wave][buf][(tau * 16 + c) * XSTR + s * 32 + quad * 8];
            uint u8[8];
            *reinterpret_cast<uint4*>(u8)     = *reinterpret_cast<const uint4*>(rp);
            *reinterpret_cast<uint4*>(u8 + 4) = *reinterpret_cast<const uint4*>(rp + 4);
            uint hh[4], ll[4];
            #pragma unroll
            for (int q = 0; q < 4; q++) {
                hh[q] = (u8[2 * q] & 0xffffu) | (u8[2 * q + 1] << 16);
                ll[q] = (u8[2 * q] >> 16) | (u8[2 * q + 1] & 0xffff0000u);
            }
            const half8 ah = __builtin_bit_cast(half8, make_uint4(hh[0], hh[1], hh[2], hh[3]));
            const half8 al = __builtin_bit_cast(half8, make_uint4(ll[0], ll[1], ll[2], ll[3]));
            #pragma unroll
            for (int t = 0; t < 4; t++) {
                accm[tau][t] = __builtin_amdgcn_mfma_f32_16x16x32_f16(ah, wh[t], accm[tau][t], 0, 0, 0);
                accl[tau][t] = __builtin_amdgcn_mfma_f32_16x16x32_f16(al, wh[t], accl[tau][t], 0, 0, 0);
                accl[tau][t] = __builtin_amdgcn_mfma_f32_16x16x32_f16(ah, wl[t], accl[tau][t], 0, 0, 0);
            }
        }
    };

    // prologue
    loadx(0, xa);
    loadx(1, xb);
    loadW(0, wh0, wl0);
    stage(0, xa);

    #pragma unroll 1
    for (int n = 0; n < NCHW; n += 2) {
        loadx(n + 2, xa);
        loadW(2 * n + 1, wh1, wl1);
        stage(1, xb);                      // chunk n+1 -> buf1
        step(0, 0, wh0, wl0);              // chunk n, s=0
        loadW(2 * n + 2, wh0, wl0);
        step(0, 1, wh1, wl1);              // chunk n, s=1
        loadx(n + 3, xb);
        loadW(2 * n + 3, wh1, wl1);
        if (n + 2 < NCHW) stage(0, xa);    // chunk n+2 -> buf0
        step(1, 0, wh0, wl0);              // chunk n+1, s=0
        loadW(2 * n + 4, wh0, wl0);
        step(1, 1, wh1, wl1);              // chunk n+1, s=1
    }

    // ---- cross-wave reduction (red aliases xbuf after barrier) ----
    __syncthreads();
    float* red = reinterpret_cast<float*>(&xbuf[0][0][0]);   // red[(w*32+row)*65 + col]
    const float scale = 1.0f / 2048.0f;
    #pragma unroll
    for (int tau = 0; tau < 2; tau++)
        #pragma unroll
        for (int t = 0; t < 4; t++)
            #pragma unroll
            for (int i = 0; i < 4; i++)
                red[(wave * 32 + tau * 16 + quad * 4 + i) * 65 + c + 16 * t] =
                    accm[tau][t][i] + accl[tau][t][i] * scale;
    __syncthreads();

    if (wave >= 2) return;

    float bvt[4];
    #pragma unroll
    for (int t = 0; t < 4; t++) bvt[t] = bias[c + 16 * t];

    #pragma unroll
    for (int i = 0; i < 4; i++) {
        const int row = wave * 16 + quad * 4 + i;
        float lt[4];
        #pragma unroll
        for (int t = 0; t < 4; t++) {
            const int col = c + 16 * t;
            lt[t] = red[(0 * 32 + row) * 65 + col] + red[(1 * 32 + row) * 65 + col]
                  + red[(2 * 32 + row) * 65 + col] + red[(3 * 32 + row) * 65 + col] + bvt[t];
        }
        const float l0 = lt[0], l1 = lt[1], l2 = lt[2], l3 = lt[3];

        float m = fmaxf(fmaxf(l0, l1), fmaxf(l2, l3));
        #pragma unroll
        for (int off = 1; off < 16; off <<= 1)
            m = fmaxf(m, __shfl_xor(m, off, 64));

        const float e0 = expf(l0 - m), e1 = expf(l1 - m);
        const float e2 = expf(l2 - m), e3 = expf(l3 - m);
        float s = e0 + e1 + e2 + e3;
        #pragma unroll
        for (int off = 1; off < 16; off <<= 1)
            s += __shfl_xor(s, off, 64);

        const float p0 = e0 / s, p1 = e1 / s, p2 = e2 / s, p3 = e3 / s;

        // keys: (prob bits << 32) | (63 - expert); experts c, c+16, c+32, c+48
        const unsigned long long ka =
            ((unsigned long long)__float_as_uint(p0) << 32) | (unsigned long long)(63 - c);
        const unsigned long long kb_ =
            ((unsigned long long)__float_as_uint(p1) << 32) | (unsigned long long)(47 - c);
        const unsigned long long kc_ =
            ((unsigned long long)__float_as_uint(p2) << 32) | (unsigned long long)(31 - c);
        const unsigned long long kd =
            ((unsigned long long)__float_as_uint(p3) << 32) | (unsigned long long)(15 - c);

        unsigned long long hi1 = ka > kb_ ? ka : kb_, lo1 = ka > kb_ ? kb_ : ka;
        unsigned long long hi2 = kc_ > kd ? kc_ : kd, lo2 = kc_ > kd ? kd : kc_;
        unsigned long long k1 = hi1 > hi2 ? hi1 : hi2;
        unsigned long long mn = hi1 > hi2 ? hi2 : hi1;
        unsigned long long mx = lo1 > lo2 ? lo1 : lo2;
        unsigned long long k2 = mn > mx ? mn : mx;

        #pragma unroll
        for (int off = 1; off < 16; off <<= 1) {
            const unsigned long long o1 = __shfl_xor(k1, off, 64);
            const unsigned long long o2 = __shfl_xor(k2, off, 64);
            const unsigned long long n1 = k1 > o1 ? k1 : o1;
            const unsigned long long w1 = k1 > o1 ? o1 : k1;   // loser of firsts
            const unsigned long long w2 = k2 > o2 ? k2 : o2;   // best of seconds
            k1 = n1;
            k2 = w1 > w2 ? w1 : w2;
        }

        if (c == 0) {
            const int gr = r0 + row;
            out[gr * 2 + 0] = (float)(63 - (int)(k1 & 0xFFFFFFFFull));
            out[gr * 2 + 1] = (float)(63 - (int)(k2 & 0xFFFFFFFFull));
            out[M_DIM * 2 + gr * 2 + 0] = __uint_as_float((unsigned)(k1 >> 32));
            out[M_DIM * 2 + gr * 2 + 1] = __uint_as_float((unsigned)(k2 >> 32));
        }
    }
}

extern "C" void kernel_launch(void* const* d_in, const int* in_sizes, int n_in,
                              void* d_out, int out_size, void* d_ws, size_t ws_size,
                              hipStream_t stream) {
    const float* x  = (const float*)d_in[0];
    const float* Wm = (const float*)d_in[1];
    const float* b  = (const float*)d_in[2];
    float* out = (float*)d_out;
    _Float16* wsT = (_Float16*)d_ws;   // 64*4*2*512*2 B = 512 KB

    split_w_kernel<<<dim3(64), dim3(256), 0, stream>>>(Wm, wsT);
    router_mfma_kernel<<<dim3(M_DIM / RM), dim3(256), 0, stream>>>(x, wsT, b, out);
}